// Round 6
// baseline (157.251 us; speedup 1.0000x reference)
//
#include <hip/hip_runtime.h>
#include <cstdint>

#define HW_ 160
#define NPIX (2*160*160)   // 51200 pixels (B*H*W)

typedef __attribute__((ext_vector_type(8))) short short8;
typedef __attribute__((ext_vector_type(4))) float f32x4;

// fp32 -> bf16 round-to-nearest-even
__device__ __forceinline__ unsigned short f2bf(float f) {
  union { float f; unsigned u; } v; v.f = f;
  unsigned r = v.u + 0x7fffu + ((v.u >> 16) & 1u);
  return (unsigned short)(r >> 16);
}
__device__ __forceinline__ float bflo(unsigned u) {
  union { unsigned u; float f; } v; v.u = u << 16; return v.f;
}
__device__ __forceinline__ float bfhi(unsigned u) {
  union { unsigned u; float f; } v; v.u = u & 0xffff0000u; return v.f;
}

__device__ __forceinline__ short8 cvt8(const float4& x0, const float4& x1) {
  short8 h;
  h[0] = (short)f2bf(x0.x); h[1] = (short)f2bf(x0.y);
  h[2] = (short)f2bf(x0.z); h[3] = (short)f2bf(x0.w);
  h[4] = (short)f2bf(x1.x); h[5] = (short)f2bf(x1.y);
  h[6] = (short)f2bf(x1.z); h[7] = (short)f2bf(x1.w);
  return h;
}

// ---------------------------------------------------------------------------
// One-time fp32 -> bf16 conversion of qkv_w (49152 elems).
// ---------------------------------------------------------------------------
__global__ __launch_bounds__(256)
void cvt_w(const float* __restrict__ qw, unsigned short* __restrict__ dst) {
  int i = (blockIdx.x * 256 + threadIdx.x) * 4;
  float4 v = *(const float4*)(qw + i);
  dst[i] = f2bf(v.x); dst[i + 1] = f2bf(v.y);
  dst[i + 2] = f2bf(v.z); dst[i + 3] = f2bf(v.w);
}

// ---------------------------------------------------------------------------
// GEMM1 (LDS-free): qt4[o/4][p] = 4 packed bf16 of sum_k x[p][k]*qkv_w[o][k].
// Grid (800, 6): block = 64 pixels x 64 outputs. No barrier anywhere:
// X fragments loaded straight from global (B-frag = x[p][kk*32+lk*8..+7]),
// W fragments from pre-converted bf16. Operand-swapped MFMA -> D row=o, col=p.
// ---------------------------------------------------------------------------
__global__ __launch_bounds__(256, 4)
void qkv_gemm(const float* __restrict__ x, const unsigned short* __restrict__ wq,
              uint2* __restrict__ qt4) {
  const int t = threadIdx.x;
  const int lane = t & 63, wv = t >> 6;
  const int wp = wv & 1, wc = wv >> 1;   // pixel-half / o-half of the 64x64 tile
  const int lr = lane & 15, lk = lane >> 4;
  const int p0 = blockIdx.x * 64;
  const int o0 = blockIdx.y * 64 + wc * 32;

  // W fragments (A-operand): rows o0+n*16+lr, k = kk*32 + lk*8 .. +7
  short8 bfr[2][4];
#pragma unroll
  for (int n = 0; n < 2; ++n) {
    const unsigned short* wr_ = wq + (size_t)(o0 + n * 16 + lr) * 128 + lk * 8;
#pragma unroll
    for (int kk = 0; kk < 4; ++kk)
      bfr[n][kk] = *(const short8*)(wr_ + kk * 32);
  }

  // X fragments (B-operand): pixel p0+wp*32+m*16+lr, k = kk*32 + lk*8 .. +7
  short8 af[2][4];
#pragma unroll
  for (int m = 0; m < 2; ++m) {
    const float* xp = x + (size_t)(p0 + wp * 32 + m * 16 + lr) * 128 + lk * 8;
#pragma unroll
    for (int kk = 0; kk < 4; ++kk) {
      float4 a0 = *(const float4*)(xp + kk * 32);
      float4 a1 = *(const float4*)(xp + kk * 32 + 4);
      af[m][kk] = cvt8(a0, a1);
    }
  }

  f32x4 acc[2][2];
#pragma unroll
  for (int n = 0; n < 2; ++n)
#pragma unroll
    for (int m = 0; m < 2; ++m) acc[n][m] = 0.f;
#pragma unroll
  for (int kk = 0; kk < 4; ++kk)
#pragma unroll
    for (int n = 0; n < 2; ++n)
#pragma unroll
      for (int m = 0; m < 2; ++m)
        acc[n][m] = __builtin_amdgcn_mfma_f32_16x16x32_bf16(
            bfr[n][kk], af[m][kk], acc[n][m], 0, 0, 0);

  // epilogue: D row = o (lk*4+i), col = pixel (lr); pack 4 o's into one uint2.
#pragma unroll
  for (int n = 0; n < 2; ++n)
#pragma unroll
    for (int m = 0; m < 2; ++m) {
      int ob = o0 + n * 16 + lk * 4;       // ob % 4 == 0
      int p = p0 + wp * 32 + m * 16 + lr;
      uint2 u;
      u.x = ((unsigned)f2bf(acc[n][m][1]) << 16) | f2bf(acc[n][m][0]);
      u.y = ((unsigned)f2bf(acc[n][m][3]) << 16) | f2bf(acc[n][m][2]);
      qt4[(size_t)(ob >> 2) * NPIX + p] = u;
    }
}

// ---------------------------------------------------------------------------
// Fused attention + output projection.
// Block = 64 pixels, 512 threads (8 waves). Wave wv: dil = wv>>2, head = wv&3,
// lane = pixel. qt4 rows hold 4 packed channels -> 8B gathers.
// y written to LDS (bf16, swizzled), then proj MFMA out of LDS.
// ---------------------------------------------------------------------------
__global__ __launch_bounds__(512, 4)
void attn_proj(const uint2* __restrict__ qt4,
               const float* __restrict__ wp_f32,
               const float* __restrict__ bias, float* __restrict__ C) {
  __shared__ short Ys[64 * 128];   // 16 KB
  __shared__ short Ws[128 * 128];  // 32 KB
  const int t = threadIdx.x;
  const int p0 = blockIdx.x * 64;

  // ---- stage proj weights fp32 -> bf16 into LDS (swizzled) ----
#pragma unroll
  for (int i = 0; i < 4; ++i) {
    int f = t + i * 512;           // 16B-chunk id (2048 total)
    int row = f >> 4;
    float4 x0 = *(const float4*)(wp_f32 + f * 8);
    float4 x1 = *(const float4*)(wp_f32 + f * 8 + 4);
    int dst = (row * 256 + (f & 15) * 16) ^ ((row & 7) << 4);
    *(short8*)((char*)Ws + dst) = cvt8(x0, x1);
  }

  // ---- attention: wave = (dil, head), lane = pixel ----
  const int lane = t & 63, wv = t >> 6;
  const int dil = wv >> 2, head = wv & 3;
  const int r = dil ? 2 : 1;
  const int p = p0 + lane;
  const int rem = p % (HW_ * HW_);
  const int yy = rem / HW_;
  const int xx = rem - yy * HW_;
  const int brow4 = dil * 16 + head * 4;   // uint2-row base (q)

  // q[16] via 4 packed 8B loads
  const uint2* qp = qt4 + (size_t)brow4 * NPIX + p;
  float q[16];
#pragma unroll
  for (int c4 = 0; c4 < 4; ++c4) {
    uint2 u = qp[(size_t)c4 * NPIX];
    q[4 * c4]     = bflo(u.x); q[4 * c4 + 1] = bfhi(u.x);
    q[4 * c4 + 2] = bflo(u.y); q[4 * c4 + 3] = bfhi(u.y);
  }

  // neighbor offsets + validity
  int np[9];
  bool val[9];
#pragma unroll
  for (int jy = 0; jy < 3; ++jy)
#pragma unroll
    for (int jx = 0; jx < 3; ++jx) {
      const int j = jy * 3 + jx;
      const int dy = (jy - 1) * r, dx = (jx - 1) * r;
      val[j] = ((unsigned)(yy + dy) < HW_) && ((unsigned)(xx + dx) < HW_);
      int q_ = p + dy * HW_ + dx;
      np[j] = min(max(q_, 0), NPIX - 1);   // clamped; garbage masked later
    }

  // logits: 36 8B gathers
  float l[9];
#pragma unroll
  for (int j = 0; j < 9; ++j) l[j] = 0.f;
  const uint2* kp = qt4 + (size_t)(32 + brow4) * NPIX;
#pragma unroll
  for (int c4 = 0; c4 < 4; ++c4) {
    const uint2* rp = kp + (size_t)c4 * NPIX;
    const float qa = q[4 * c4], qb = q[4 * c4 + 1];
    const float qc = q[4 * c4 + 2], qd = q[4 * c4 + 3];
#pragma unroll
    for (int j = 0; j < 9; ++j) {
      uint2 u = rp[np[j]];
      l[j] += qa * bflo(u.x) + qb * bfhi(u.x) + qc * bflo(u.y) + qd * bfhi(u.y);
    }
  }
#pragma unroll
  for (int j = 0; j < 9; ++j) l[j] = val[j] ? l[j] * 0.25f : 0.f;  // zero-pad

  // softmax over all 9 (invalid logits participate as 0, per reference)
  float mx = l[0];
#pragma unroll
  for (int j = 1; j < 9; ++j) mx = fmaxf(mx, l[j]);
  float e[9], s = 0.f;
#pragma unroll
  for (int j = 0; j < 9; ++j) { e[j] = __expf(l[j] - mx); s += e[j]; }
#pragma unroll
  for (int j = 0; j < 9; ++j) if (!val[j]) e[j] = 0.f;  // v_j = 0 for OOB
  const float inv = 1.0f / s;

  // o[c] = sum_j e_j * v_j[c]: 36 8B gathers
  float o[16];
#pragma unroll
  for (int c = 0; c < 16; ++c) o[c] = 0.f;
  const uint2* vp = qt4 + (size_t)(64 + brow4) * NPIX;
#pragma unroll
  for (int c4 = 0; c4 < 4; ++c4) {
    const uint2* rp = vp + (size_t)c4 * NPIX;
#pragma unroll
    for (int j = 0; j < 9; ++j) {
      uint2 u = rp[np[j]];
      o[4 * c4]     += e[j] * bflo(u.x);
      o[4 * c4 + 1] += e[j] * bfhi(u.x);
      o[4 * c4 + 2] += e[j] * bflo(u.y);
      o[4 * c4 + 3] += e[j] * bfhi(u.y);
    }
  }

  // write y-slice to LDS: row = lane, cols [dil*64+head*16, +16), swizzled
  {
    short8 h0, h1;
#pragma unroll
    for (int c = 0; c < 8; ++c) h0[c] = (short)f2bf(o[c] * inv);
#pragma unroll
    for (int c = 0; c < 8; ++c) h1[c] = (short)f2bf(o[c + 8] * inv);
    int colb = (dil * 64 + head * 16) * 2;
    int base = (lane * 256 + colb) ^ ((lane & 7) << 4);
    *(short8*)((char*)Ys + base) = h0;
    int base2 = (lane * 256 + colb + 16) ^ ((lane & 7) << 4);
    *(short8*)((char*)Ys + base2) = h1;
  }
  __syncthreads();

  // ---- proj: wave -> (pixel-quarter wq_, o-half wo) ----
  const int wq_ = wv & 3, wo = wv >> 2;
  const int lr = lane & 15, lk = lane >> 4;

  short8 a[4];
#pragma unroll
  for (int kk = 0; kk < 4; ++kk) {
    int row = wq_ * 16 + lr;
    int off = (row * 256 + kk * 64 + lk * 16) ^ ((row & 7) << 4);
    a[kk] = *(const short8*)((const char*)Ys + off);
  }

  f32x4 acc[4];
#pragma unroll
  for (int n = 0; n < 4; ++n) acc[n] = 0.f;
#pragma unroll
  for (int kk = 0; kk < 4; ++kk) {
    short8 b[4];
#pragma unroll
    for (int n = 0; n < 4; ++n) {
      int row = wo * 64 + n * 16 + lr;
      int off = (row * 256 + kk * 64 + lk * 16) ^ ((row & 7) << 4);
      b[n] = *(const short8*)((const char*)Ws + off);
    }
#pragma unroll
    for (int n = 0; n < 4; ++n)
      acc[n] = __builtin_amdgcn_mfma_f32_16x16x32_bf16(a[kk], b[n], acc[n], 0, 0, 0);
  }

#pragma unroll
  for (int n = 0; n < 4; ++n) {
    int ccol = wo * 64 + n * 16 + lr;
    float bv = bias[ccol];
    int crow = p0 + wq_ * 16 + lk * 4;
#pragma unroll
    for (int i = 0; i < 4; ++i)
      C[(size_t)(crow + i) * 128 + ccol] = acc[n][i] + bv;
  }
}

extern "C" void kernel_launch(void* const* d_in, const int* in_sizes, int n_in,
                              void* d_out, int out_size, void* d_ws, size_t ws_size,
                              hipStream_t stream) {
  const float* x      = (const float*)d_in[0];  // [2,160,160,128]
  const float* qkv_w  = (const float*)d_in[1];  // [384,128]
  const float* proj_w = (const float*)d_in[2];  // [128,128]
  const float* proj_b = (const float*)d_in[3];  // [128]
  float* out = (float*)d_out;                   // [2,160,160,128] fp32

  uint2* qt4 = (uint2*)d_ws;                                  // [96][51200] uint2, 39.3 MB
  unsigned short* wqbf = (unsigned short*)(qt4 + (size_t)96 * NPIX);  // [384][128] bf16

  // 0) qkv weight conversion fp32 -> bf16
  cvt_w<<<48, 256, 0, stream>>>(qkv_w, wqbf);

  // 1) QKV projection (LDS-free) -> packed transposed bf16 qt4[o/4][p]
  qkv_gemm<<<dim3(NPIX / 64, 6), 256, 0, stream>>>(x, wqbf, qt4);

  // 2+3) Fused dilated neighborhood attention + output projection
  attn_proj<<<NPIX / 64, 512, 0, stream>>>(qt4, proj_w, proj_b, out);
}

// Round 7
// 134.410 us; speedup vs baseline: 1.1699x; 1.1699x over previous
//
#include <hip/hip_runtime.h>
#include <cstdint>

#define HW_ 160
#define NPIX (2*160*160)   // 51200 pixels (B*H*W)

typedef __attribute__((ext_vector_type(8))) short short8;
typedef __attribute__((ext_vector_type(4))) float f32x4;

// fp32 -> bf16 round-to-nearest-even
__device__ __forceinline__ unsigned short f2bf(float f) {
  union { float f; unsigned u; } v; v.f = f;
  unsigned r = v.u + 0x7fffu + ((v.u >> 16) & 1u);
  return (unsigned short)(r >> 16);
}
__device__ __forceinline__ float bflo(unsigned u) {
  union { unsigned u; float f; } v; v.u = u << 16; return v.f;
}
__device__ __forceinline__ float bfhi(unsigned u) {
  union { unsigned u; float f; } v; v.u = u & 0xffff0000u; return v.f;
}

__device__ __forceinline__ short8 cvt8(const float4& x0, const float4& x1) {
  short8 h;
  h[0] = (short)f2bf(x0.x); h[1] = (short)f2bf(x0.y);
  h[2] = (short)f2bf(x0.z); h[3] = (short)f2bf(x0.w);
  h[4] = (short)f2bf(x1.x); h[5] = (short)f2bf(x1.y);
  h[6] = (short)f2bf(x1.z); h[7] = (short)f2bf(x1.w);
  return h;
}

// ---------------------------------------------------------------------------
// One-time fp32 -> bf16 conversion: qkv_w (49152) then x (6553600).
// 49152 = 48*1024, so no intra-block divergence at the boundary.
// ---------------------------------------------------------------------------
__global__ __launch_bounds__(256)
void cvt_all(const float* __restrict__ qw, const float* __restrict__ x,
             unsigned short* __restrict__ wdst, unsigned short* __restrict__ xdst) {
  int i = (blockIdx.x * 256 + threadIdx.x) * 4;
  if (i < 49152) {
    float4 v = *(const float4*)(qw + i);
    ushort4 h;
    h.x = f2bf(v.x); h.y = f2bf(v.y); h.z = f2bf(v.z); h.w = f2bf(v.w);
    *(ushort4*)(wdst + i) = h;
  } else {
    int j = i - 49152;
    float4 v = *(const float4*)(x + j);
    ushort4 h;
    h.x = f2bf(v.x); h.y = f2bf(v.y); h.z = f2bf(v.z); h.w = f2bf(v.w);
    *(ushort4*)(xdst + j) = h;
  }
}

// ---------------------------------------------------------------------------
// GEMM1: qt4[o/4][p] = 4 packed bf16 of sum_k x[p][k]*qkv_w[o][k].
// Block = 64 pixels x 192 outputs (3 o-tiles); grid (800, 2).
// x staged once via global_load_lds (width 16) with PRE-SWIZZLED source:
// LDS dest linear, global src xor'd with ((row&7)<<4) — involution, row-
// preserving, so reads use the same xor (rule-21 both-sides pattern).
// it-0 W fragments prefetched before the barrier. uint2-packed epilogue.
// ---------------------------------------------------------------------------
__global__ __launch_bounds__(256, 3)
void qkv_gemm(const unsigned short* __restrict__ xbf,
              const unsigned short* __restrict__ wq,
              uint2* __restrict__ qt4) {
  __shared__ short As[64 * 128];  // 16 KB
  const int t = threadIdx.x;
  const int p0 = blockIdx.x * 64;
  const int og = blockIdx.y;      // o-group: 0 -> [0,192), 1 -> [192,384)

  const int lane = t & 63, wv = t >> 6;
  const int wp = wv & 1, wc = wv >> 1;   // pixel-half / o-half
  const int lr = lane & 15, lk = lane >> 4;

  // ---- prefetch it=0 W fragments (independent of LDS/barrier) ----
  const unsigned short* wbase =
      wq + (size_t)(og * 192 + wc * 32 + lr) * 128 + lk * 8;
  short8 bfr0[2][4];
#pragma unroll
  for (int n = 0; n < 2; ++n)
#pragma unroll
    for (int kk = 0; kk < 4; ++kk)
      bfr0[n][kk] = *(const short8*)(wbase + n * 16 * 128 + kk * 32);

  // ---- stage x tile (64 rows x 256 B) via global_load_lds, preswz src ----
  {
    const char* gx = (const char*)(xbf + (size_t)p0 * 128);
#pragma unroll
    for (int i = 0; i < 4; ++i) {
      int f = i * 256 + t;                    // 16B-chunk id
      int row = f >> 4;
      int src = (f * 16) ^ ((row & 7) << 4);  // row-preserving involution
      __builtin_amdgcn_global_load_lds(
          (const __attribute__((address_space(1))) unsigned int*)(gx + src),
          (__attribute__((address_space(3))) unsigned int*)
              ((char*)As + i * 4096 + wv * 1024),   // wave-uniform base
          16, 0, 0);
    }
  }
  __syncthreads();

  // ---- pixel fragments from LDS (swizzled reads) ----
  short8 af[2][4];
#pragma unroll
  for (int m = 0; m < 2; ++m)
#pragma unroll
    for (int kk = 0; kk < 4; ++kk) {
      int row = wp * 32 + m * 16 + lr;
      int off = (row * 256 + kk * 64 + lk * 16) ^ ((row & 7) << 4);
      af[m][kk] = *(const short8*)((const char*)As + off);
    }

#pragma unroll
  for (int it = 0; it < 3; ++it) {
    short8 bfr[2][4];
    if (it == 0) {
#pragma unroll
      for (int n = 0; n < 2; ++n)
#pragma unroll
        for (int kk = 0; kk < 4; ++kk) bfr[n][kk] = bfr0[n][kk];
    } else {
#pragma unroll
      for (int n = 0; n < 2; ++n)
#pragma unroll
        for (int kk = 0; kk < 4; ++kk)
          bfr[n][kk] = *(const short8*)(wbase + (it * 64 + n * 16) * 128 + kk * 32);
    }

    f32x4 acc[2][2];
#pragma unroll
    for (int n = 0; n < 2; ++n)
#pragma unroll
      for (int m = 0; m < 2; ++m) acc[n][m] = 0.f;
#pragma unroll
    for (int kk = 0; kk < 4; ++kk)
#pragma unroll
      for (int n = 0; n < 2; ++n)
#pragma unroll
        for (int m = 0; m < 2; ++m)
          acc[n][m] = __builtin_amdgcn_mfma_f32_16x16x32_bf16(
              bfr[n][kk], af[m][kk], acc[n][m], 0, 0, 0);

    // epilogue: D row = o (lk*4+i), col = pixel (lr); 4 o's per uint2.
    const int o0 = og * 192 + it * 64 + wc * 32;
#pragma unroll
    for (int n = 0; n < 2; ++n)
#pragma unroll
      for (int m = 0; m < 2; ++m) {
        int ob = o0 + n * 16 + lk * 4;       // ob % 4 == 0
        int p = p0 + wp * 32 + m * 16 + lr;
        uint2 u;
        u.x = ((unsigned)f2bf(acc[n][m][1]) << 16) | f2bf(acc[n][m][0]);
        u.y = ((unsigned)f2bf(acc[n][m][3]) << 16) | f2bf(acc[n][m][2]);
        qt4[(size_t)(ob >> 2) * NPIX + p] = u;
      }
  }
}

// ---------------------------------------------------------------------------
// Fused attention + output projection (round-6 proven, unchanged).
// Block = 64 pixels, 512 threads (8 waves). Wave wv: dil = wv>>2, head = wv&3,
// lane = pixel. qt4 rows hold 4 packed channels -> 8B gathers.
// ---------------------------------------------------------------------------
__global__ __launch_bounds__(512, 4)
void attn_proj(const uint2* __restrict__ qt4,
               const float* __restrict__ wp_f32,
               const float* __restrict__ bias, float* __restrict__ C) {
  __shared__ short Ys[64 * 128];   // 16 KB
  __shared__ short Ws[128 * 128];  // 32 KB
  const int t = threadIdx.x;
  const int p0 = blockIdx.x * 64;

  // ---- stage proj weights fp32 -> bf16 into LDS (swizzled) ----
#pragma unroll
  for (int i = 0; i < 4; ++i) {
    int f = t + i * 512;           // 16B-chunk id (2048 total)
    int row = f >> 4;
    float4 x0 = *(const float4*)(wp_f32 + f * 8);
    float4 x1 = *(const float4*)(wp_f32 + f * 8 + 4);
    int dst = (row * 256 + (f & 15) * 16) ^ ((row & 7) << 4);
    *(short8*)((char*)Ws + dst) = cvt8(x0, x1);
  }

  // ---- attention: wave = (dil, head), lane = pixel ----
  const int lane = t & 63, wv = t >> 6;
  const int dil = wv >> 2, head = wv & 3;
  const int r = dil ? 2 : 1;
  const int p = p0 + lane;
  const int rem = p % (HW_ * HW_);
  const int yy = rem / HW_;
  const int xx = rem - yy * HW_;
  const int brow4 = dil * 16 + head * 4;   // uint2-row base (q)

  // q[16] via 4 packed 8B loads
  const uint2* qp = qt4 + (size_t)brow4 * NPIX + p;
  float q[16];
#pragma unroll
  for (int c4 = 0; c4 < 4; ++c4) {
    uint2 u = qp[(size_t)c4 * NPIX];
    q[4 * c4]     = bflo(u.x); q[4 * c4 + 1] = bfhi(u.x);
    q[4 * c4 + 2] = bflo(u.y); q[4 * c4 + 3] = bfhi(u.y);
  }

  // neighbor offsets + validity
  int np[9];
  bool val[9];
#pragma unroll
  for (int jy = 0; jy < 3; ++jy)
#pragma unroll
    for (int jx = 0; jx < 3; ++jx) {
      const int j = jy * 3 + jx;
      const int dy = (jy - 1) * r, dx = (jx - 1) * r;
      val[j] = ((unsigned)(yy + dy) < HW_) && ((unsigned)(xx + dx) < HW_);
      int q_ = p + dy * HW_ + dx;
      np[j] = min(max(q_, 0), NPIX - 1);   // clamped; garbage masked later
    }

  // logits: 36 8B gathers
  float l[9];
#pragma unroll
  for (int j = 0; j < 9; ++j) l[j] = 0.f;
  const uint2* kp = qt4 + (size_t)(32 + brow4) * NPIX;
#pragma unroll
  for (int c4 = 0; c4 < 4; ++c4) {
    const uint2* rp = kp + (size_t)c4 * NPIX;
    const float qa = q[4 * c4], qb = q[4 * c4 + 1];
    const float qc = q[4 * c4 + 2], qd = q[4 * c4 + 3];
#pragma unroll
    for (int j = 0; j < 9; ++j) {
      uint2 u = rp[np[j]];
      l[j] += qa * bflo(u.x) + qb * bfhi(u.x) + qc * bflo(u.y) + qd * bfhi(u.y);
    }
  }
#pragma unroll
  for (int j = 0; j < 9; ++j) l[j] = val[j] ? l[j] * 0.25f : 0.f;  // zero-pad

  // softmax over all 9 (invalid logits participate as 0, per reference)
  float mx = l[0];
#pragma unroll
  for (int j = 1; j < 9; ++j) mx = fmaxf(mx, l[j]);
  float e[9], s = 0.f;
#pragma unroll
  for (int j = 0; j < 9; ++j) { e[j] = __expf(l[j] - mx); s += e[j]; }
#pragma unroll
  for (int j = 0; j < 9; ++j) if (!val[j]) e[j] = 0.f;  // v_j = 0 for OOB
  const float inv = 1.0f / s;

  // o[c] = sum_j e_j * v_j[c]: 36 8B gathers
  float o[16];
#pragma unroll
  for (int c = 0; c < 16; ++c) o[c] = 0.f;
  const uint2* vp = qt4 + (size_t)(64 + brow4) * NPIX;
#pragma unroll
  for (int c4 = 0; c4 < 4; ++c4) {
    const uint2* rp = vp + (size_t)c4 * NPIX;
#pragma unroll
    for (int j = 0; j < 9; ++j) {
      uint2 u = rp[np[j]];
      o[4 * c4]     += e[j] * bflo(u.x);
      o[4 * c4 + 1] += e[j] * bfhi(u.x);
      o[4 * c4 + 2] += e[j] * bflo(u.y);
      o[4 * c4 + 3] += e[j] * bfhi(u.y);
    }
  }

  // write y-slice to LDS: row = lane, cols [dil*64+head*16, +16), swizzled
  {
    short8 h0, h1;
#pragma unroll
    for (int c = 0; c < 8; ++c) h0[c] = (short)f2bf(o[c] * inv);
#pragma unroll
    for (int c = 0; c < 8; ++c) h1[c] = (short)f2bf(o[c + 8] * inv);
    int colb = (dil * 64 + head * 16) * 2;
    int base = (lane * 256 + colb) ^ ((lane & 7) << 4);
    *(short8*)((char*)Ys + base) = h0;
    int base2 = (lane * 256 + colb + 16) ^ ((lane & 7) << 4);
    *(short8*)((char*)Ys + base2) = h1;
  }
  __syncthreads();

  // ---- proj: wave -> (pixel-quarter wq_, o-half wo) ----
  const int wq_ = wv & 3, wo = wv >> 2;
  const int lr = lane & 15, lk = lane >> 4;

  short8 a[4];
#pragma unroll
  for (int kk = 0; kk < 4; ++kk) {
    int row = wq_ * 16 + lr;
    int off = (row * 256 + kk * 64 + lk * 16) ^ ((row & 7) << 4);
    a[kk] = *(const short8*)((const char*)Ys + off);
  }

  f32x4 acc[4];
#pragma unroll
  for (int n = 0; n < 4; ++n) acc[n] = 0.f;
#pragma unroll
  for (int kk = 0; kk < 4; ++kk) {
    short8 b[4];
#pragma unroll
    for (int n = 0; n < 4; ++n) {
      int row = wo * 64 + n * 16 + lr;
      int off = (row * 256 + kk * 64 + lk * 16) ^ ((row & 7) << 4);
      b[n] = *(const short8*)((const char*)Ws + off);
    }
#pragma unroll
    for (int n = 0; n < 4; ++n)
      acc[n] = __builtin_amdgcn_mfma_f32_16x16x32_bf16(a[kk], b[n], acc[n], 0, 0, 0);
  }

#pragma unroll
  for (int n = 0; n < 4; ++n) {
    int ccol = wo * 64 + n * 16 + lr;
    float bv = bias[ccol];
    int crow = p0 + wq_ * 16 + lk * 4;
#pragma unroll
    for (int i = 0; i < 4; ++i)
      C[(size_t)(crow + i) * 128 + ccol] = acc[n][i] + bv;
  }
}

extern "C" void kernel_launch(void* const* d_in, const int* in_sizes, int n_in,
                              void* d_out, int out_size, void* d_ws, size_t ws_size,
                              hipStream_t stream) {
  const float* x      = (const float*)d_in[0];  // [2,160,160,128]
  const float* qkv_w  = (const float*)d_in[1];  // [384,128]
  const float* proj_w = (const float*)d_in[2];  // [128,128]
  const float* proj_b = (const float*)d_in[3];  // [128]
  float* out = (float*)d_out;                   // [2,160,160,128] fp32

  uint2* qt4 = (uint2*)d_ws;                                   // [96][51200] uint2, 39.3 MB
  unsigned short* wqbf = (unsigned short*)(qt4 + (size_t)96 * NPIX);  // [384][128] bf16
  unsigned short* xbf  = wqbf + 49152;                         // [51200][128] bf16, 13.1 MB

  // 0) fp32 -> bf16: qkv weights + x  (6602752 elems = 6448 * 1024)
  cvt_all<<<6448, 256, 0, stream>>>(qkv_w, x, wqbf, xbf);

  // 1) QKV projection -> packed transposed bf16 qt4[o/4][p]
  qkv_gemm<<<dim3(NPIX / 64, 2), 256, 0, stream>>>(xbf, wqbf, qt4);

  // 2+3) Fused dilated neighborhood attention + output projection
  attn_proj<<<NPIX / 64, 512, 0, stream>>>(qt4, proj_w, proj_b, out);
}

// Round 9
// 134.197 us; speedup vs baseline: 1.1718x; 1.0016x over previous
//
#include <hip/hip_runtime.h>
#include <cstdint>

#define HW_ 160
#define NPIX (2*160*160)   // 51200 pixels (B*H*W)

typedef __attribute__((ext_vector_type(8))) short short8;
typedef __attribute__((ext_vector_type(4))) float f32x4;

// fp32 -> bf16 round-to-nearest-even
__device__ __forceinline__ unsigned short f2bf(float f) {
  union { float f; unsigned u; } v; v.f = f;
  unsigned r = v.u + 0x7fffu + ((v.u >> 16) & 1u);
  return (unsigned short)(r >> 16);
}
__device__ __forceinline__ float bflo(unsigned u) {
  union { unsigned u; float f; } v; v.u = u << 16; return v.f;
}
__device__ __forceinline__ float bfhi(unsigned u) {
  union { unsigned u; float f; } v; v.u = u & 0xffff0000u; return v.f;
}

__device__ __forceinline__ short8 cvt8(const float4& x0, const float4& x1) {
  short8 h;
  h[0] = (short)f2bf(x0.x); h[1] = (short)f2bf(x0.y);
  h[2] = (short)f2bf(x0.z); h[3] = (short)f2bf(x0.w);
  h[4] = (short)f2bf(x1.x); h[5] = (short)f2bf(x1.y);
  h[6] = (short)f2bf(x1.z); h[7] = (short)f2bf(x1.w);
  return h;
}

// ---------------------------------------------------------------------------
// One-time fp32 -> bf16 conversion of qkv_w only (49152 elems, 48 blocks).
// ---------------------------------------------------------------------------
__global__ __launch_bounds__(256)
void cvt_w(const float* __restrict__ qw, unsigned short* __restrict__ dst) {
  int i = (blockIdx.x * 256 + threadIdx.x) * 4;
  float4 v = *(const float4*)(qw + i);
  ushort4 h;
  h.x = f2bf(v.x); h.y = f2bf(v.y); h.z = f2bf(v.z); h.w = f2bf(v.w);
  *(ushort4*)(dst + i) = h;
}

// ---------------------------------------------------------------------------
// GEMM1: qt4[o/4][p] = 4 packed bf16 of sum_k x[p][k]*qkv_w[o][k].
// Block = 128 pixels x 192 outputs; grid (400, 2); 512 threads (8 waves =
// 4 pixel-quarters x 2 o-halves). x read fp32 ONCE per block, converted in
// registers during staging (no separate x-conversion pass). Each wave
// prefetches ALL its W fragments (bf16) before the barrier -> post-barrier
// phase is pure ds_read + MFMA + store. Operand-swapped MFMA: D row=o, col=p.
// ---------------------------------------------------------------------------
__global__ __launch_bounds__(512, 2)
void qkv_gemm(const float* __restrict__ x, const unsigned short* __restrict__ wq,
              uint2* __restrict__ qt4) {
  __shared__ short As[128 * 128];  // 32 KB, xor-swizzled
  const int t = threadIdx.x;
  const int p0 = blockIdx.x * 128;
  const int og = blockIdx.y;       // o-group: 0 -> [0,192), 1 -> [192,384)

  const int lane = t & 63, wv = t >> 6;
  const int wpx = wv & 3, wo = wv >> 2;  // pixel-quarter / o-half
  const int lr = lane & 15, lk = lane >> 4;

  // ---- issue x-tile loads (fp32, 2 float4 per 16B-bf16 chunk) ----
  const float* A = x + (size_t)p0 * 128;
  float4 xr[4][2];
#pragma unroll
  for (int i = 0; i < 4; ++i) {
    int f = t + i * 512;               // chunk id, 2048 total (128 rows x 16)
    xr[i][0] = *(const float4*)(A + f * 8);
    xr[i][1] = *(const float4*)(A + f * 8 + 4);
  }

  // ---- prefetch ALL W fragments for this wave (independent of barrier) ----
  const unsigned short* wbase =
      wq + (size_t)(og * 192 + wo * 96 + lr) * 128 + lk * 8;
  short8 bfr[3][2][4];
#pragma unroll
  for (int it = 0; it < 3; ++it)
#pragma unroll
    for (int n = 0; n < 2; ++n)
#pragma unroll
      for (int kk = 0; kk < 4; ++kk)
        bfr[it][n][kk] = *(const short8*)(wbase + (it * 32 + n * 16) * 128 + kk * 32);

  // ---- convert + stage into LDS (swizzled) ----
#pragma unroll
  for (int i = 0; i < 4; ++i) {
    int f = t + i * 512;
    int row = f >> 4;
    int dst = (row * 256 + (f & 15) * 16) ^ ((row & 7) << 4);
    *(short8*)((char*)As + dst) = cvt8(xr[i][0], xr[i][1]);
  }
  __syncthreads();

  // ---- pixel fragments from LDS ----
  short8 af[2][4];
#pragma unroll
  for (int m = 0; m < 2; ++m)
#pragma unroll
    for (int kk = 0; kk < 4; ++kk) {
      int row = wpx * 32 + m * 16 + lr;
      int off = (row * 256 + kk * 64 + lk * 16) ^ ((row & 7) << 4);
      af[m][kk] = *(const short8*)((const char*)As + off);
    }

#pragma unroll
  for (int it = 0; it < 3; ++it) {
    f32x4 acc[2][2];
#pragma unroll
    for (int n = 0; n < 2; ++n)
#pragma unroll
      for (int m = 0; m < 2; ++m) acc[n][m] = 0.f;
#pragma unroll
    for (int kk = 0; kk < 4; ++kk)
#pragma unroll
      for (int n = 0; n < 2; ++n)
#pragma unroll
        for (int m = 0; m < 2; ++m)
          acc[n][m] = __builtin_amdgcn_mfma_f32_16x16x32_bf16(
              bfr[it][n][kk], af[m][kk], acc[n][m], 0, 0, 0);

    // epilogue: D row = o (lk*4+i), col = pixel (lr); 4 o's per uint2.
    const int o0 = og * 192 + wo * 96 + it * 32;
#pragma unroll
    for (int n = 0; n < 2; ++n)
#pragma unroll
      for (int m = 0; m < 2; ++m) {
        int ob = o0 + n * 16 + lk * 4;       // ob % 4 == 0
        int p = p0 + wpx * 32 + m * 16 + lr;
        uint2 u;
        u.x = ((unsigned)f2bf(acc[n][m][1]) << 16) | f2bf(acc[n][m][0]);
        u.y = ((unsigned)f2bf(acc[n][m][3]) << 16) | f2bf(acc[n][m][2]);
        qt4[(size_t)(ob >> 2) * NPIX + p] = u;
      }
  }
}

// ---------------------------------------------------------------------------
// Fused attention + output projection (round-6/7 proven, unchanged).
// Block = 64 pixels, 512 threads (8 waves). Wave wv: dil = wv>>2, head = wv&3,
// lane = pixel. qt4 rows hold 4 packed channels -> 8B gathers.
// ---------------------------------------------------------------------------
__global__ __launch_bounds__(512, 4)
void attn_proj(const uint2* __restrict__ qt4,
               const float* __restrict__ wp_f32,
               const float* __restrict__ bias, float* __restrict__ C) {
  __shared__ short Ys[64 * 128];   // 16 KB
  __shared__ short Ws[128 * 128];  // 32 KB
  const int t = threadIdx.x;
  const int p0 = blockIdx.x * 64;

  // ---- stage proj weights fp32 -> bf16 into LDS (swizzled) ----
#pragma unroll
  for (int i = 0; i < 4; ++i) {
    int f = t + i * 512;           // 16B-chunk id (2048 total)
    int row = f >> 4;
    float4 x0 = *(const float4*)(wp_f32 + f * 8);
    float4 x1 = *(const float4*)(wp_f32 + f * 8 + 4);
    int dst = (row * 256 + (f & 15) * 16) ^ ((row & 7) << 4);
    *(short8*)((char*)Ws + dst) = cvt8(x0, x1);
  }

  // ---- attention: wave = (dil, head), lane = pixel ----
  const int lane = t & 63, wv = t >> 6;
  const int dil = wv >> 2, head = wv & 3;
  const int r = dil ? 2 : 1;
  const int p = p0 + lane;
  const int rem = p % (HW_ * HW_);
  const int yy = rem / HW_;
  const int xx = rem - yy * HW_;
  const int brow4 = dil * 16 + head * 4;   // uint2-row base (q)

  // q[16] via 4 packed 8B loads
  const uint2* qp = qt4 + (size_t)brow4 * NPIX + p;
  float q[16];
#pragma unroll
  for (int c4 = 0; c4 < 4; ++c4) {
    uint2 u = qp[(size_t)c4 * NPIX];
    q[4 * c4]     = bflo(u.x); q[4 * c4 + 1] = bfhi(u.x);
    q[4 * c4 + 2] = bflo(u.y); q[4 * c4 + 3] = bfhi(u.y);
  }

  // neighbor offsets + validity
  int np[9];
  bool val[9];
#pragma unroll
  for (int jy = 0; jy < 3; ++jy)
#pragma unroll
    for (int jx = 0; jx < 3; ++jx) {
      const int j = jy * 3 + jx;
      const int dy = (jy - 1) * r, dx = (jx - 1) * r;
      val[j] = ((unsigned)(yy + dy) < HW_) && ((unsigned)(xx + dx) < HW_);
      int q_ = p + dy * HW_ + dx;
      np[j] = min(max(q_, 0), NPIX - 1);   // clamped; garbage masked later
    }

  // logits: 36 8B gathers
  float l[9];
#pragma unroll
  for (int j = 0; j < 9; ++j) l[j] = 0.f;
  const uint2* kp = qt4 + (size_t)(32 + brow4) * NPIX;
#pragma unroll
  for (int c4 = 0; c4 < 4; ++c4) {
    const uint2* rp = kp + (size_t)c4 * NPIX;
    const float qa = q[4 * c4], qb = q[4 * c4 + 1];
    const float qc = q[4 * c4 + 2], qd = q[4 * c4 + 3];
#pragma unroll
    for (int j = 0; j < 9; ++j) {
      uint2 u = rp[np[j]];
      l[j] += qa * bflo(u.x) + qb * bfhi(u.x) + qc * bflo(u.y) + qd * bfhi(u.y);
    }
  }
#pragma unroll
  for (int j = 0; j < 9; ++j) l[j] = val[j] ? l[j] * 0.25f : 0.f;  // zero-pad

  // softmax over all 9 (invalid logits participate as 0, per reference)
  float mx = l[0];
#pragma unroll
  for (int j = 1; j < 9; ++j) mx = fmaxf(mx, l[j]);
  float e[9], s = 0.f;
#pragma unroll
  for (int j = 0; j < 9; ++j) { e[j] = __expf(l[j] - mx); s += e[j]; }
#pragma unroll
  for (int j = 0; j < 9; ++j) if (!val[j]) e[j] = 0.f;  // v_j = 0 for OOB
  const float inv = 1.0f / s;

  // o[c] = sum_j e_j * v_j[c]: 36 8B gathers
  float o[16];
#pragma unroll
  for (int c = 0; c < 16; ++c) o[c] = 0.f;
  const uint2* vp = qt4 + (size_t)(64 + brow4) * NPIX;
#pragma unroll
  for (int c4 = 0; c4 < 4; ++c4) {
    const uint2* rp = vp + (size_t)c4 * NPIX;
#pragma unroll
    for (int j = 0; j < 9; ++j) {
      uint2 u = rp[np[j]];
      o[4 * c4]     += e[j] * bflo(u.x);
      o[4 * c4 + 1] += e[j] * bfhi(u.x);
      o[4 * c4 + 2] += e[j] * bflo(u.y);
      o[4 * c4 + 3] += e[j] * bfhi(u.y);
    }
  }

  // write y-slice to LDS: row = lane, cols [dil*64+head*16, +16), swizzled
  {
    short8 h0, h1;
#pragma unroll
    for (int c = 0; c < 8; ++c) h0[c] = (short)f2bf(o[c] * inv);
#pragma unroll
    for (int c = 0; c < 8; ++c) h1[c] = (short)f2bf(o[c + 8] * inv);
    int colb = (dil * 64 + head * 16) * 2;
    int base = (lane * 256 + colb) ^ ((lane & 7) << 4);
    *(short8*)((char*)Ys + base) = h0;
    int base2 = (lane * 256 + colb + 16) ^ ((lane & 7) << 4);
    *(short8*)((char*)Ys + base2) = h1;
  }
  __syncthreads();

  // ---- proj: wave -> (pixel-quarter wq_, o-half wo) ----
  const int wq_ = wv & 3, wo = wv >> 2;
  const int lr = lane & 15, lk = lane >> 4;

  short8 a[4];
#pragma unroll
  for (int kk = 0; kk < 4; ++kk) {
    int row = wq_ * 16 + lr;
    int off = (row * 256 + kk * 64 + lk * 16) ^ ((row & 7) << 4);
    a[kk] = *(const short8*)((const char*)Ys + off);
  }

  f32x4 acc[4];
#pragma unroll
  for (int n = 0; n < 4; ++n) acc[n] = 0.f;
#pragma unroll
  for (int kk = 0; kk < 4; ++kk) {
    short8 b[4];
#pragma unroll
    for (int n = 0; n < 4; ++n) {
      int row = wo * 64 + n * 16 + lr;
      int off = (row * 256 + kk * 64 + lk * 16) ^ ((row & 7) << 4);
      b[n] = *(const short8*)((const char*)Ws + off);
    }
#pragma unroll
    for (int n = 0; n < 4; ++n)
      acc[n] = __builtin_amdgcn_mfma_f32_16x16x32_bf16(a[kk], b[n], acc[n], 0, 0, 0);
  }

#pragma unroll
  for (int n = 0; n < 4; ++n) {
    int ccol = wo * 64 + n * 16 + lr;
    float bv = bias[ccol];
    int crow = p0 + wq_ * 16 + lk * 4;
#pragma unroll
    for (int i = 0; i < 4; ++i)
      C[(size_t)(crow + i) * 128 + ccol] = acc[n][i] + bv;
  }
}

extern "C" void kernel_launch(void* const* d_in, const int* in_sizes, int n_in,
                              void* d_out, int out_size, void* d_ws, size_t ws_size,
                              hipStream_t stream) {
  const float* x      = (const float*)d_in[0];  // [2,160,160,128]
  const float* qkv_w  = (const float*)d_in[1];  // [384,128]
  const float* proj_w = (const float*)d_in[2];  // [128,128]
  const float* proj_b = (const float*)d_in[3];  // [128]
  float* out = (float*)d_out;                   // [2,160,160,128] fp32

  uint2* qt4 = (uint2*)d_ws;                                   // [96][51200] uint2, 39.3 MB
  unsigned short* wqbf = (unsigned short*)(qt4 + (size_t)96 * NPIX);  // [384][128] bf16

  // 0) qkv weight conversion fp32 -> bf16 (tiny)
  cvt_w<<<48, 256, 0, stream>>>(qkv_w, wqbf);

  // 1) QKV projection (x converted in-staging) -> packed bf16 qt4[o/4][p]
  qkv_gemm<<<dim3(NPIX / 128, 2), 512, 0, stream>>>(x, wqbf, qt4);

  // 2+3) Fused dilated neighborhood attention + output projection
  attn_proj<<<NPIX / 64, 512, 0, stream>>>(qt4, proj_w, proj_b, out);
}

// Round 10
// 130.361 us; speedup vs baseline: 1.2063x; 1.0294x over previous
//
#include <hip/hip_runtime.h>
#include <cstdint>

#define HW_ 160
#define NPIX (2*160*160)   // 51200 pixels (B*H*W)

typedef __attribute__((ext_vector_type(8))) short short8;
typedef __attribute__((ext_vector_type(4))) float f32x4;

// fp32 -> bf16 round-to-nearest-even
__device__ __forceinline__ unsigned short f2bf(float f) {
  union { float f; unsigned u; } v; v.f = f;
  unsigned r = v.u + 0x7fffu + ((v.u >> 16) & 1u);
  return (unsigned short)(r >> 16);
}
__device__ __forceinline__ float bflo(unsigned u) {
  union { unsigned u; float f; } v; v.u = u << 16; return v.f;
}
__device__ __forceinline__ float bfhi(unsigned u) {
  union { unsigned u; float f; } v; v.u = u & 0xffff0000u; return v.f;
}

__device__ __forceinline__ short8 cvt8(const float4& x0, const float4& x1) {
  short8 h;
  h[0] = (short)f2bf(x0.x); h[1] = (short)f2bf(x0.y);
  h[2] = (short)f2bf(x0.z); h[3] = (short)f2bf(x0.w);
  h[4] = (short)f2bf(x1.x); h[5] = (short)f2bf(x1.y);
  h[6] = (short)f2bf(x1.z); h[7] = (short)f2bf(x1.w);
  return h;
}

// Bijective XCD-chunk swizzle for 800-block grids (800 = 8 XCDs x 100):
// consecutive swizzled tiles stay on one XCD -> neighbor-halo L2 locality.
__device__ __forceinline__ int swz800(int b) { return (b & 7) * 100 + (b >> 3); }

// ---------------------------------------------------------------------------
// One-time fp32 -> bf16 conversion: qkv_w (49152) then x (6553600).
// 49152 = 48*1024, so no intra-block divergence at the boundary.
// ---------------------------------------------------------------------------
__global__ __launch_bounds__(256)
void cvt_all(const float* __restrict__ qw, const float* __restrict__ x,
             unsigned short* __restrict__ wdst, unsigned short* __restrict__ xdst) {
  int i = (blockIdx.x * 256 + threadIdx.x) * 4;
  if (i < 49152) {
    float4 v = *(const float4*)(qw + i);
    ushort4 h;
    h.x = f2bf(v.x); h.y = f2bf(v.y); h.z = f2bf(v.z); h.w = f2bf(v.w);
    *(ushort4*)(wdst + i) = h;
  } else {
    int j = i - 49152;
    float4 v = *(const float4*)(x + j);
    ushort4 h;
    h.x = f2bf(v.x); h.y = f2bf(v.y); h.z = f2bf(v.z); h.w = f2bf(v.w);
    *(ushort4*)(xdst + j) = h;
  }
}

// ---------------------------------------------------------------------------
// GEMM1: qt4[o/4][p] = 4 packed bf16 of sum_k x[p][k]*qkv_w[o][k].
// Block = 64 pixels x 192 outputs (3 o-tiles); grid (800, 2).
// x staged once via global_load_lds (width 16) with PRE-SWIZZLED source
// (rule-21 both-sides pattern). W fragments for it0 AND it1 prefetched while
// the DMA is in flight; it2 loads inside the loop. uint2-packed epilogue.
// XCD-swizzled pixel-tile index (matches attn_proj's).
// ---------------------------------------------------------------------------
__global__ __launch_bounds__(256, 3)
void qkv_gemm(const unsigned short* __restrict__ xbf,
              const unsigned short* __restrict__ wq,
              uint2* __restrict__ qt4) {
  __shared__ short As[64 * 128];  // 16 KB
  const int t = threadIdx.x;
  const int p0 = swz800(blockIdx.x) * 64;
  const int og = blockIdx.y;      // o-group: 0 -> [0,192), 1 -> [192,384)

  const int lane = t & 63, wv = t >> 6;
  const int wp = wv & 1, wc = wv >> 1;   // pixel-half / o-half
  const int lr = lane & 15, lk = lane >> 4;

  // ---- stage x tile (64 rows x 256 B) via global_load_lds, preswz src ----
  {
    const char* gx = (const char*)(xbf + (size_t)p0 * 128);
#pragma unroll
    for (int i = 0; i < 4; ++i) {
      int f = i * 256 + t;                    // 16B-chunk id
      int row = f >> 4;
      int src = (f * 16) ^ ((row & 7) << 4);  // row-preserving involution
      __builtin_amdgcn_global_load_lds(
          (const __attribute__((address_space(1))) unsigned int*)(gx + src),
          (__attribute__((address_space(3))) unsigned int*)
              ((char*)As + i * 4096 + wv * 1024),   // wave-uniform base
          16, 0, 0);
    }
  }

  // ---- prefetch it0 + it1 W fragments while DMA is in flight ----
  const unsigned short* wbase =
      wq + (size_t)(og * 192 + wc * 32 + lr) * 128 + lk * 8;
  short8 bfr0[2][4], bfr1[2][4];
#pragma unroll
  for (int n = 0; n < 2; ++n)
#pragma unroll
    for (int kk = 0; kk < 4; ++kk) {
      bfr0[n][kk] = *(const short8*)(wbase + n * 16 * 128 + kk * 32);
      bfr1[n][kk] = *(const short8*)(wbase + (64 + n * 16) * 128 + kk * 32);
    }
  __syncthreads();

  // ---- pixel fragments from LDS (swizzled reads) ----
  short8 af[2][4];
#pragma unroll
  for (int m = 0; m < 2; ++m)
#pragma unroll
    for (int kk = 0; kk < 4; ++kk) {
      int row = wp * 32 + m * 16 + lr;
      int off = (row * 256 + kk * 64 + lk * 16) ^ ((row & 7) << 4);
      af[m][kk] = *(const short8*)((const char*)As + off);
    }

#pragma unroll
  for (int it = 0; it < 3; ++it) {
    short8 bfr[2][4];
    if (it == 0) {
#pragma unroll
      for (int n = 0; n < 2; ++n)
#pragma unroll
        for (int kk = 0; kk < 4; ++kk) bfr[n][kk] = bfr0[n][kk];
    } else if (it == 1) {
#pragma unroll
      for (int n = 0; n < 2; ++n)
#pragma unroll
        for (int kk = 0; kk < 4; ++kk) bfr[n][kk] = bfr1[n][kk];
    } else {
#pragma unroll
      for (int n = 0; n < 2; ++n)
#pragma unroll
        for (int kk = 0; kk < 4; ++kk)
          bfr[n][kk] = *(const short8*)(wbase + (128 + n * 16) * 128 + kk * 32);
    }

    f32x4 acc[2][2];
#pragma unroll
    for (int n = 0; n < 2; ++n)
#pragma unroll
      for (int m = 0; m < 2; ++m) acc[n][m] = 0.f;
#pragma unroll
    for (int kk = 0; kk < 4; ++kk)
#pragma unroll
      for (int n = 0; n < 2; ++n)
#pragma unroll
        for (int m = 0; m < 2; ++m)
          acc[n][m] = __builtin_amdgcn_mfma_f32_16x16x32_bf16(
              bfr[n][kk], af[m][kk], acc[n][m], 0, 0, 0);

    // epilogue: D row = o (lk*4+i), col = pixel (lr); 4 o's per uint2.
    const int o0 = og * 192 + it * 64 + wc * 32;
#pragma unroll
    for (int n = 0; n < 2; ++n)
#pragma unroll
      for (int m = 0; m < 2; ++m) {
        int ob = o0 + n * 16 + lk * 4;       // ob % 4 == 0
        int p = p0 + wp * 32 + m * 16 + lr;
        uint2 u;
        u.x = ((unsigned)f2bf(acc[n][m][1]) << 16) | f2bf(acc[n][m][0]);
        u.y = ((unsigned)f2bf(acc[n][m][3]) << 16) | f2bf(acc[n][m][2]);
        qt4[(size_t)(ob >> 2) * NPIX + p] = u;
      }
  }
}

// ---------------------------------------------------------------------------
// Fused attention + output projection (round-7 proven; + XCD swizzle).
// Block = 64 pixels, 512 threads (8 waves). Wave wv: dil = wv>>2, head = wv&3,
// lane = pixel. qt4 rows hold 4 packed channels -> 8B gathers.
// ---------------------------------------------------------------------------
__global__ __launch_bounds__(512, 4)
void attn_proj(const uint2* __restrict__ qt4,
               const float* __restrict__ wp_f32,
               const float* __restrict__ bias, float* __restrict__ C) {
  __shared__ short Ys[64 * 128];   // 16 KB
  __shared__ short Ws[128 * 128];  // 32 KB
  const int t = threadIdx.x;
  const int p0 = swz800(blockIdx.x) * 64;

  // ---- stage proj weights fp32 -> bf16 into LDS (swizzled) ----
#pragma unroll
  for (int i = 0; i < 4; ++i) {
    int f = t + i * 512;           // 16B-chunk id (2048 total)
    int row = f >> 4;
    float4 x0 = *(const float4*)(wp_f32 + f * 8);
    float4 x1 = *(const float4*)(wp_f32 + f * 8 + 4);
    int dst = (row * 256 + (f & 15) * 16) ^ ((row & 7) << 4);
    *(short8*)((char*)Ws + dst) = cvt8(x0, x1);
  }

  // ---- attention: wave = (dil, head), lane = pixel ----
  const int lane = t & 63, wv = t >> 6;
  const int dil = wv >> 2, head = wv & 3;
  const int r = dil ? 2 : 1;
  const int p = p0 + lane;
  const int rem = p % (HW_ * HW_);
  const int yy = rem / HW_;
  const int xx = rem - yy * HW_;
  const int brow4 = dil * 16 + head * 4;   // uint2-row base (q)

  // q[16] via 4 packed 8B loads
  const uint2* qp = qt4 + (size_t)brow4 * NPIX + p;
  float q[16];
#pragma unroll
  for (int c4 = 0; c4 < 4; ++c4) {
    uint2 u = qp[(size_t)c4 * NPIX];
    q[4 * c4]     = bflo(u.x); q[4 * c4 + 1] = bfhi(u.x);
    q[4 * c4 + 2] = bflo(u.y); q[4 * c4 + 3] = bfhi(u.y);
  }

  // neighbor offsets + validity
  int np[9];
  bool val[9];
#pragma unroll
  for (int jy = 0; jy < 3; ++jy)
#pragma unroll
    for (int jx = 0; jx < 3; ++jx) {
      const int j = jy * 3 + jx;
      const int dy = (jy - 1) * r, dx = (jx - 1) * r;
      val[j] = ((unsigned)(yy + dy) < HW_) && ((unsigned)(xx + dx) < HW_);
      int q_ = p + dy * HW_ + dx;
      np[j] = min(max(q_, 0), NPIX - 1);   // clamped; garbage masked later
    }

  // logits: 36 8B gathers
  float l[9];
#pragma unroll
  for (int j = 0; j < 9; ++j) l[j] = 0.f;
  const uint2* kp = qt4 + (size_t)(32 + brow4) * NPIX;
#pragma unroll
  for (int c4 = 0; c4 < 4; ++c4) {
    const uint2* rp = kp + (size_t)c4 * NPIX;
    const float qa = q[4 * c4], qb = q[4 * c4 + 1];
    const float qc = q[4 * c4 + 2], qd = q[4 * c4 + 3];
#pragma unroll
    for (int j = 0; j < 9; ++j) {
      uint2 u = rp[np[j]];
      l[j] += qa * bflo(u.x) + qb * bfhi(u.x) + qc * bflo(u.y) + qd * bfhi(u.y);
    }
  }
#pragma unroll
  for (int j = 0; j < 9; ++j) l[j] = val[j] ? l[j] * 0.25f : 0.f;  // zero-pad

  // softmax over all 9 (invalid logits participate as 0, per reference)
  float mx = l[0];
#pragma unroll
  for (int j = 1; j < 9; ++j) mx = fmaxf(mx, l[j]);
  float e[9], s = 0.f;
#pragma unroll
  for (int j = 0; j < 9; ++j) { e[j] = __expf(l[j] - mx); s += e[j]; }
#pragma unroll
  for (int j = 0; j < 9; ++j) if (!val[j]) e[j] = 0.f;  // v_j = 0 for OOB
  const float inv = 1.0f / s;

  // o[c] = sum_j e_j * v_j[c]: 36 8B gathers
  float o[16];
#pragma unroll
  for (int c = 0; c < 16; ++c) o[c] = 0.f;
  const uint2* vp = qt4 + (size_t)(64 + brow4) * NPIX;
#pragma unroll
  for (int c4 = 0; c4 < 4; ++c4) {
    const uint2* rp = vp + (size_t)c4 * NPIX;
#pragma unroll
    for (int j = 0; j < 9; ++j) {
      uint2 u = rp[np[j]];
      o[4 * c4]     += e[j] * bflo(u.x);
      o[4 * c4 + 1] += e[j] * bfhi(u.x);
      o[4 * c4 + 2] += e[j] * bflo(u.y);
      o[4 * c4 + 3] += e[j] * bfhi(u.y);
    }
  }

  // write y-slice to LDS: row = lane, cols [dil*64+head*16, +16), swizzled
  {
    short8 h0, h1;
#pragma unroll
    for (int c = 0; c < 8; ++c) h0[c] = (short)f2bf(o[c] * inv);
#pragma unroll
    for (int c = 0; c < 8; ++c) h1[c] = (short)f2bf(o[c + 8] * inv);
    int colb = (dil * 64 + head * 16) * 2;
    int base = (lane * 256 + colb) ^ ((lane & 7) << 4);
    *(short8*)((char*)Ys + base) = h0;
    int base2 = (lane * 256 + colb + 16) ^ ((lane & 7) << 4);
    *(short8*)((char*)Ys + base2) = h1;
  }
  __syncthreads();

  // ---- proj: wave -> (pixel-quarter wq_, o-half wo) ----
  const int wq_ = wv & 3, wo = wv >> 2;
  const int lr = lane & 15, lk = lane >> 4;

  short8 a[4];
#pragma unroll
  for (int kk = 0; kk < 4; ++kk) {
    int row = wq_ * 16 + lr;
    int off = (row * 256 + kk * 64 + lk * 16) ^ ((row & 7) << 4);
    a[kk] = *(const short8*)((const char*)Ys + off);
  }

  f32x4 acc[4];
#pragma unroll
  for (int n = 0; n < 4; ++n) acc[n] = 0.f;
#pragma unroll
  for (int kk = 0; kk < 4; ++kk) {
    short8 b[4];
#pragma unroll
    for (int n = 0; n < 4; ++n) {
      int row = wo * 64 + n * 16 + lr;
      int off = (row * 256 + kk * 64 + lk * 16) ^ ((row & 7) << 4);
      b[n] = *(const short8*)((const char*)Ws + off);
    }
#pragma unroll
    for (int n = 0; n < 4; ++n)
      acc[n] = __builtin_amdgcn_mfma_f32_16x16x32_bf16(a[kk], b[n], acc[n], 0, 0, 0);
  }

#pragma unroll
  for (int n = 0; n < 4; ++n) {
    int ccol = wo * 64 + n * 16 + lr;
    float bv = bias[ccol];
    int crow = p0 + wq_ * 16 + lk * 4;
#pragma unroll
    for (int i = 0; i < 4; ++i)
      C[(size_t)(crow + i) * 128 + ccol] = acc[n][i] + bv;
  }
}

extern "C" void kernel_launch(void* const* d_in, const int* in_sizes, int n_in,
                              void* d_out, int out_size, void* d_ws, size_t ws_size,
                              hipStream_t stream) {
  const float* x      = (const float*)d_in[0];  // [2,160,160,128]
  const float* qkv_w  = (const float*)d_in[1];  // [384,128]
  const float* proj_w = (const float*)d_in[2];  // [128,128]
  const float* proj_b = (const float*)d_in[3];  // [128]
  float* out = (float*)d_out;                   // [2,160,160,128] fp32

  uint2* qt4 = (uint2*)d_ws;                                   // [96][51200] uint2, 39.3 MB
  unsigned short* wqbf = (unsigned short*)(qt4 + (size_t)96 * NPIX);  // [384][128] bf16
  unsigned short* xbf  = wqbf + 49152;                         // [51200][128] bf16, 13.1 MB

  // 0) fp32 -> bf16: qkv weights + x  (6602752 elems = 6448 * 1024)
  cvt_all<<<6448, 256, 0, stream>>>(qkv_w, x, wqbf, xbf);

  // 1) QKV projection -> packed transposed bf16 qt4[o/4][p]
  qkv_gemm<<<dim3(NPIX / 64, 2), 256, 0, stream>>>(xbf, wqbf, qt4);

  // 2+3) Fused dilated neighborhood attention + output projection
  attn_proj<<<NPIX / 64, 512, 0, stream>>>(qt4, proj_w, proj_b, out);
}

// Round 11
// 127.478 us; speedup vs baseline: 1.2336x; 1.0226x over previous
//
#include <hip/hip_runtime.h>
#include <cstdint>

#define HW_ 160
#define NPIX (2*160*160)   // 51200 pixels (B*H*W)

typedef __attribute__((ext_vector_type(8))) short short8;
typedef __attribute__((ext_vector_type(4))) float f32x4;

// fp32 -> bf16 round-to-nearest-even
__device__ __forceinline__ unsigned short f2bf(float f) {
  union { float f; unsigned u; } v; v.f = f;
  unsigned r = v.u + 0x7fffu + ((v.u >> 16) & 1u);
  return (unsigned short)(r >> 16);
}
__device__ __forceinline__ float bflo(unsigned u) {
  union { unsigned u; float f; } v; v.u = u << 16; return v.f;
}
__device__ __forceinline__ float bfhi(unsigned u) {
  union { unsigned u; float f; } v; v.u = u & 0xffff0000u; return v.f;
}

__device__ __forceinline__ short8 cvt8(const float4& x0, const float4& x1) {
  short8 h;
  h[0] = (short)f2bf(x0.x); h[1] = (short)f2bf(x0.y);
  h[2] = (short)f2bf(x0.z); h[3] = (short)f2bf(x0.w);
  h[4] = (short)f2bf(x1.x); h[5] = (short)f2bf(x1.y);
  h[6] = (short)f2bf(x1.z); h[7] = (short)f2bf(x1.w);
  return h;
}

// Bijective XCD-chunk swizzle for 800-block grids (800 = 8 XCDs x 100):
// consecutive swizzled tiles stay on one XCD -> neighbor-halo L2 locality.
__device__ __forceinline__ int swz800(int b) { return (b & 7) * 100 + (b >> 3); }

// ---------------------------------------------------------------------------
// One-time fp32 -> bf16 conversion of qkv_w only (49152 elems, 48 blocks).
// ---------------------------------------------------------------------------
__global__ __launch_bounds__(256)
void cvt_w(const float* __restrict__ qw, unsigned short* __restrict__ dst) {
  int i = (blockIdx.x * 256 + threadIdx.x) * 4;
  float4 v = *(const float4*)(qw + i);
  ushort4 h;
  h.x = f2bf(v.x); h.y = f2bf(v.y); h.z = f2bf(v.z); h.w = f2bf(v.w);
  *(ushort4*)(dst + i) = h;
}

// ---------------------------------------------------------------------------
// GEMM1: qt4[o/4][p] = 4 packed bf16 of sum_k x[p][k]*qkv_w[o][k].
// Block = 64 pixels x 192 outputs (3 o-tiles); grid (800, 2).
// x staged as FP32 (32 KB) via 8x global_load_lds with PRE-SWIZZLED source
// ((f*16)^((row&7)<<4), row-preserving involution within the 512B row);
// fp32->bf16 conversion happens at fragment-read time (no cvt pass for x).
// W fragments it0+it1 prefetched while the DMA is in flight. uint2 epilogue.
// XCD-swizzled pixel-tile index (matches attn_proj's).
// ---------------------------------------------------------------------------
__global__ __launch_bounds__(256, 3)
void qkv_gemm(const float* __restrict__ x,
              const unsigned short* __restrict__ wq,
              uint2* __restrict__ qt4) {
  __shared__ float As[64 * 128];  // 32 KB fp32, xor-swizzled
  const int t = threadIdx.x;
  const int p0 = swz800(blockIdx.x) * 64;
  const int og = blockIdx.y;      // o-group: 0 -> [0,192), 1 -> [192,384)

  const int lane = t & 63, wv = t >> 6;
  const int wp = wv & 1, wc = wv >> 1;   // pixel-half / o-half
  const int lr = lane & 15, lk = lane >> 4;

  // ---- stage x tile (64 rows x 512 B) via global_load_lds, preswz src ----
  {
    const char* gx = (const char*)(x + (size_t)p0 * 128);
#pragma unroll
    for (int i = 0; i < 8; ++i) {
      int f = i * 256 + t;                    // 16B-chunk id (2048 total)
      int row = f >> 5;                       // 32 chunks per 512B row
      int src = (f * 16) ^ ((row & 7) << 4);  // row-preserving involution
      __builtin_amdgcn_global_load_lds(
          (const __attribute__((address_space(1))) unsigned int*)(gx + src),
          (__attribute__((address_space(3))) unsigned int*)
              ((char*)As + i * 4096 + wv * 1024),   // wave-uniform base
          16, 0, 0);
    }
  }

  // ---- prefetch it0 + it1 W fragments while DMA is in flight ----
  const unsigned short* wbase =
      wq + (size_t)(og * 192 + wc * 32 + lr) * 128 + lk * 8;
  short8 bfr0[2][4], bfr1[2][4];
#pragma unroll
  for (int n = 0; n < 2; ++n)
#pragma unroll
    for (int kk = 0; kk < 4; ++kk) {
      bfr0[n][kk] = *(const short8*)(wbase + n * 16 * 128 + kk * 32);
      bfr1[n][kk] = *(const short8*)(wbase + (64 + n * 16) * 128 + kk * 32);
    }
  __syncthreads();

  // ---- pixel fragments: fp32 LDS reads (swizzled) + in-reg bf16 convert ----
  short8 af[2][4];
#pragma unroll
  for (int m = 0; m < 2; ++m)
#pragma unroll
    for (int kk = 0; kk < 4; ++kk) {
      int row = wp * 32 + m * 16 + lr;
      int b0 = (row * 512 + kk * 128 + lk * 32) ^ ((row & 7) << 4);
      int b1 = (row * 512 + kk * 128 + lk * 32 + 16) ^ ((row & 7) << 4);
      float4 f0 = *(const float4*)((const char*)As + b0);
      float4 f1 = *(const float4*)((const char*)As + b1);
      af[m][kk] = cvt8(f0, f1);
    }

#pragma unroll
  for (int it = 0; it < 3; ++it) {
    short8 bfr[2][4];
    if (it == 0) {
#pragma unroll
      for (int n = 0; n < 2; ++n)
#pragma unroll
        for (int kk = 0; kk < 4; ++kk) bfr[n][kk] = bfr0[n][kk];
    } else if (it == 1) {
#pragma unroll
      for (int n = 0; n < 2; ++n)
#pragma unroll
        for (int kk = 0; kk < 4; ++kk) bfr[n][kk] = bfr1[n][kk];
    } else {
#pragma unroll
      for (int n = 0; n < 2; ++n)
#pragma unroll
        for (int kk = 0; kk < 4; ++kk)
          bfr[n][kk] = *(const short8*)(wbase + (128 + n * 16) * 128 + kk * 32);
    }

    f32x4 acc[2][2];
#pragma unroll
    for (int n = 0; n < 2; ++n)
#pragma unroll
      for (int m = 0; m < 2; ++m) acc[n][m] = 0.f;
#pragma unroll
    for (int kk = 0; kk < 4; ++kk)
#pragma unroll
      for (int n = 0; n < 2; ++n)
#pragma unroll
        for (int m = 0; m < 2; ++m)
          acc[n][m] = __builtin_amdgcn_mfma_f32_16x16x32_bf16(
              bfr[n][kk], af[m][kk], acc[n][m], 0, 0, 0);

    // epilogue: D row = o (lk*4+i), col = pixel (lr); 4 o's per uint2.
    const int o0 = og * 192 + it * 64 + wc * 32;
#pragma unroll
    for (int n = 0; n < 2; ++n)
#pragma unroll
      for (int m = 0; m < 2; ++m) {
        int ob = o0 + n * 16 + lk * 4;       // ob % 4 == 0
        int p = p0 + wp * 32 + m * 16 + lr;
        uint2 u;
        u.x = ((unsigned)f2bf(acc[n][m][1]) << 16) | f2bf(acc[n][m][0]);
        u.y = ((unsigned)f2bf(acc[n][m][3]) << 16) | f2bf(acc[n][m][2]);
        qt4[(size_t)(ob >> 2) * NPIX + p] = u;
      }
  }
}

// ---------------------------------------------------------------------------
// Fused attention + output projection (round-10 proven, unchanged).
// Block = 64 pixels, 512 threads (8 waves). Wave wv: dil = wv>>2, head = wv&3,
// lane = pixel. qt4 rows hold 4 packed channels -> 8B gathers.
// ---------------------------------------------------------------------------
__global__ __launch_bounds__(512, 4)
void attn_proj(const uint2* __restrict__ qt4,
               const float* __restrict__ wp_f32,
               const float* __restrict__ bias, float* __restrict__ C) {
  __shared__ short Ys[64 * 128];   // 16 KB
  __shared__ short Ws[128 * 128];  // 32 KB
  const int t = threadIdx.x;
  const int p0 = swz800(blockIdx.x) * 64;

  // ---- stage proj weights fp32 -> bf16 into LDS (swizzled) ----
#pragma unroll
  for (int i = 0; i < 4; ++i) {
    int f = t + i * 512;           // 16B-chunk id (2048 total)
    int row = f >> 4;
    float4 x0 = *(const float4*)(wp_f32 + f * 8);
    float4 x1 = *(const float4*)(wp_f32 + f * 8 + 4);
    int dst = (row * 256 + (f & 15) * 16) ^ ((row & 7) << 4);
    *(short8*)((char*)Ws + dst) = cvt8(x0, x1);
  }

  // ---- attention: wave = (dil, head), lane = pixel ----
  const int lane = t & 63, wv = t >> 6;
  const int dil = wv >> 2, head = wv & 3;
  const int r = dil ? 2 : 1;
  const int p = p0 + lane;
  const int rem = p % (HW_ * HW_);
  const int yy = rem / HW_;
  const int xx = rem - yy * HW_;
  const int brow4 = dil * 16 + head * 4;   // uint2-row base (q)

  // q[16] via 4 packed 8B loads
  const uint2* qp = qt4 + (size_t)brow4 * NPIX + p;
  float q[16];
#pragma unroll
  for (int c4 = 0; c4 < 4; ++c4) {
    uint2 u = qp[(size_t)c4 * NPIX];
    q[4 * c4]     = bflo(u.x); q[4 * c4 + 1] = bfhi(u.x);
    q[4 * c4 + 2] = bflo(u.y); q[4 * c4 + 3] = bfhi(u.y);
  }

  // neighbor offsets + validity
  int np[9];
  bool val[9];
#pragma unroll
  for (int jy = 0; jy < 3; ++jy)
#pragma unroll
    for (int jx = 0; jx < 3; ++jx) {
      const int j = jy * 3 + jx;
      const int dy = (jy - 1) * r, dx = (jx - 1) * r;
      val[j] = ((unsigned)(yy + dy) < HW_) && ((unsigned)(xx + dx) < HW_);
      int q_ = p + dy * HW_ + dx;
      np[j] = min(max(q_, 0), NPIX - 1);   // clamped; garbage masked later
    }

  // logits: 36 8B gathers
  float l[9];
#pragma unroll
  for (int j = 0; j < 9; ++j) l[j] = 0.f;
  const uint2* kp = qt4 + (size_t)(32 + brow4) * NPIX;
#pragma unroll
  for (int c4 = 0; c4 < 4; ++c4) {
    const uint2* rp = kp + (size_t)c4 * NPIX;
    const float qa = q[4 * c4], qb = q[4 * c4 + 1];
    const float qc = q[4 * c4 + 2], qd = q[4 * c4 + 3];
#pragma unroll
    for (int j = 0; j < 9; ++j) {
      uint2 u = rp[np[j]];
      l[j] += qa * bflo(u.x) + qb * bfhi(u.x) + qc * bflo(u.y) + qd * bfhi(u.y);
    }
  }
#pragma unroll
  for (int j = 0; j < 9; ++j) l[j] = val[j] ? l[j] * 0.25f : 0.f;  // zero-pad

  // softmax over all 9 (invalid logits participate as 0, per reference)
  float mx = l[0];
#pragma unroll
  for (int j = 1; j < 9; ++j) mx = fmaxf(mx, l[j]);
  float e[9], s = 0.f;
#pragma unroll
  for (int j = 0; j < 9; ++j) { e[j] = __expf(l[j] - mx); s += e[j]; }
#pragma unroll
  for (int j = 0; j < 9; ++j) if (!val[j]) e[j] = 0.f;  // v_j = 0 for OOB
  const float inv = 1.0f / s;

  // o[c] = sum_j e_j * v_j[c]: 36 8B gathers
  float o[16];
#pragma unroll
  for (int c = 0; c < 16; ++c) o[c] = 0.f;
  const uint2* vp = qt4 + (size_t)(64 + brow4) * NPIX;
#pragma unroll
  for (int c4 = 0; c4 < 4; ++c4) {
    const uint2* rp = vp + (size_t)c4 * NPIX;
#pragma unroll
    for (int j = 0; j < 9; ++j) {
      uint2 u = rp[np[j]];
      o[4 * c4]     += e[j] * bflo(u.x);
      o[4 * c4 + 1] += e[j] * bfhi(u.x);
      o[4 * c4 + 2] += e[j] * bflo(u.y);
      o[4 * c4 + 3] += e[j] * bfhi(u.y);
    }
  }

  // write y-slice to LDS: row = lane, cols [dil*64+head*16, +16), swizzled
  {
    short8 h0, h1;
#pragma unroll
    for (int c = 0; c < 8; ++c) h0[c] = (short)f2bf(o[c] * inv);
#pragma unroll
    for (int c = 0; c < 8; ++c) h1[c] = (short)f2bf(o[c + 8] * inv);
    int colb = (dil * 64 + head * 16) * 2;
    int base = (lane * 256 + colb) ^ ((lane & 7) << 4);
    *(short8*)((char*)Ys + base) = h0;
    int base2 = (lane * 256 + colb + 16) ^ ((lane & 7) << 4);
    *(short8*)((char*)Ys + base2) = h1;
  }
  __syncthreads();

  // ---- proj: wave -> (pixel-quarter wq_, o-half wo) ----
  const int wq_ = wv & 3, wo = wv >> 2;
  const int lr = lane & 15, lk = lane >> 4;

  short8 a[4];
#pragma unroll
  for (int kk = 0; kk < 4; ++kk) {
    int row = wq_ * 16 + lr;
    int off = (row * 256 + kk * 64 + lk * 16) ^ ((row & 7) << 4);
    a[kk] = *(const short8*)((const char*)Ys + off);
  }

  f32x4 acc[4];
#pragma unroll
  for (int n = 0; n < 4; ++n) acc[n] = 0.f;
#pragma unroll
  for (int kk = 0; kk < 4; ++kk) {
    short8 b[4];
#pragma unroll
    for (int n = 0; n < 4; ++n) {
      int row = wo * 64 + n * 16 + lr;
      int off = (row * 256 + kk * 64 + lk * 16) ^ ((row & 7) << 4);
      b[n] = *(const short8*)((const char*)Ws + off);
    }
#pragma unroll
    for (int n = 0; n < 4; ++n)
      acc[n] = __builtin_amdgcn_mfma_f32_16x16x32_bf16(a[kk], b[n], acc[n], 0, 0, 0);
  }

#pragma unroll
  for (int n = 0; n < 4; ++n) {
    int ccol = wo * 64 + n * 16 + lr;
    float bv = bias[ccol];
    int crow = p0 + wq_ * 16 + lk * 4;
#pragma unroll
    for (int i = 0; i < 4; ++i)
      C[(size_t)(crow + i) * 128 + ccol] = acc[n][i] + bv;
  }
}

extern "C" void kernel_launch(void* const* d_in, const int* in_sizes, int n_in,
                              void* d_out, int out_size, void* d_ws, size_t ws_size,
                              hipStream_t stream) {
  const float* x      = (const float*)d_in[0];  // [2,160,160,128]
  const float* qkv_w  = (const float*)d_in[1];  // [384,128]
  const float* proj_w = (const float*)d_in[2];  // [128,128]
  const float* proj_b = (const float*)d_in[3];  // [128]
  float* out = (float*)d_out;                   // [2,160,160,128] fp32

  uint2* qt4 = (uint2*)d_ws;                                   // [96][51200] uint2, 39.3 MB
  unsigned short* wqbf = (unsigned short*)(qt4 + (size_t)96 * NPIX);  // [384][128] bf16

  // 0) qkv weight conversion fp32 -> bf16 (tiny, 48 blocks)
  cvt_w<<<48, 256, 0, stream>>>(qkv_w, wqbf);

  // 1) QKV projection (x fp32 staged direct, cvt at fragment read) -> qt4
  qkv_gemm<<<dim3(NPIX / 64, 2), 256, 0, stream>>>(x, wqbf, qt4);

  // 2+3) Fused dilated neighborhood attention + output projection
  attn_proj<<<NPIX / 64, 512, 0, stream>>>(qt4, proj_w, proj_b, out);
}